// Round 7
// baseline (163.502 us; speedup 1.0000x reference)
//
#include <hip/hip_runtime.h>

typedef unsigned short u16;
typedef float f32x4 __attribute__((ext_vector_type(4)));
typedef short short8 __attribute__((ext_vector_type(8)));

#define B_ 32
#define N_ 1024
#define D_ 512
#define K_ 64
#define KG_ 80
#define MT_ 32768          // total rows B*N

__device__ __forceinline__ u16 f2bf(float f) {
  union { float f; unsigned u; } x; x.f = f;
  unsigned u = x.u;
  u += 0x7FFFu + ((u >> 16) & 1u);          // RNE, finite data
  return (u16)(u >> 16);
}
__device__ __forceinline__ void split2(float v, u16& h, u16& l) {
  union { float f; unsigned u; } x; x.f = v;
  unsigned hu = x.u & 0xFFFF0000u;          // truncate -> hi
  h = (u16)(hu >> 16);
  union { unsigned u; float f; } hf; hf.u = hu;
  l = f2bf(v - hf.f);                       // exact remainder, rne -> lo
}

// ---------------------------------------------------------------------------
// K0: BN fold; zero accumulators; pack clusters into MFMA fragments (hi/lo).
// cpk layout: [kk=16][h=2][cf=5][lane=64][j=8] u16
//   element = clusters[d=kk*32+(lane>>4)*8+j][col=cf*16+(lane&15)]
// (A- and B-fragment lane packings are identical, so this serves the new
//  A-operand role unchanged — verified byte-identical to rounds 5/6.)
// ---------------------------------------------------------------------------
__global__ void k_prep(const float* __restrict__ clusters,
                       const float* __restrict__ bn_w, const float* __restrict__ bn_b,
                       const float* __restrict__ bn_m, const float* __restrict__ bn_v,
                       u16* __restrict__ cpk, float* __restrict__ bn_sc,
                       float* __restrict__ bn_sh,
                       float* __restrict__ asum, float* __restrict__ ssq) {
  int t = blockIdx.x * 256 + threadIdx.x;
  if (t < KG_) {
    float sc = bn_w[t] * rsqrtf(bn_v[t] + 1e-5f);
    bn_sc[t] = sc;
    bn_sh[t] = bn_b[t] - bn_m[t] * sc;
  }
  if (t < B_ * K_) asum[t] = 0.0f;
  if (t < B_) ssq[t] = 0.0f;
  if (t < 5120) {                            // (kk*5+cf)*64 + lane
    int grp = t >> 6;
    int kk = grp / 5, cf = grp % 5;
    int lane = t & 63;
    int col = cf * 16 + (lane & 15);
#pragma unroll
    for (int j = 0; j < 8; j++) {
      int d = kk * 32 + ((lane >> 4) << 3) + j;
      float v = clusters[(size_t)d * 80 + col];
      u16 h, l; split2(v, h, l);
      cpk[(size_t)kk * 5120 + ((0 * 5 + cf) * 64 + lane) * 8 + j] = h;
      cpk[(size_t)kk * 5120 + ((1 * 5 + cf) * 64 + lane) * 8 + j] = l;
    }
  }
}

// ---------------------------------------------------------------------------
// K1 (MFMA, logits^T orientation): C[c=80][n] = clusters^T x^T.
// A = cpk fragments (L2-hot, direct loads). B = x rows, NATURAL layout:
// lane l15 = n-column, elems = 8 consecutive d -> 2x16B loads, depth-8
// register prefetch (512 B/wave in flight -> HBM-rate streaming).
// Also emits xT[d][n] bf16 (rne) for k_vlad, 8x 2B stores/step.
// Softmax per n: lane-local 20 c + shfl_xor(16,32). aT via small LDS bounce.
// 512 blocks x 256 thr (4 waves x 16 n), no K-loop barriers.
// ---------------------------------------------------------------------------
__global__ __launch_bounds__(256, 3) void k_assign(
    const float* __restrict__ x, const u16* __restrict__ cpk,
    const float* __restrict__ bn_sc, const float* __restrict__ bn_sh,
    u16* __restrict__ aT, u16* __restrict__ xT, float* __restrict__ asum_g) {
  __shared__ u16 aTs[64][72];       // [c][n_local], pad 72 (row=144B)

  int t = threadIdx.x;
  int lane = t & 63;
  int w = t >> 6;
  int l15 = lane & 15, lhi = lane >> 4;
  int n0 = blockIdx.x * 64;
  int b = blockIdx.x >> 4;          // 16 blocks per batch
  int nw = n0 + w * 16 + l15;       // this lane's n (C column)

  const float* xrow = x + (size_t)nw * 512 + lhi * 8;

  f32x4 acc[5];
#pragma unroll
  for (int cf = 0; cf < 5; cf++) acc[cf] = (f32x4)0.0f;

  f32x4 xq[8][2];
#pragma unroll
  for (int p = 0; p < 8; p++) {
    xq[p][0] = *(const f32x4*)(xrow + p * 32);
    xq[p][1] = *(const f32x4*)(xrow + p * 32 + 4);
  }

#pragma unroll
  for (int kk = 0; kk < 16; kk++) {
    // A fragments (clusters, hi/lo) — direct global, L2-resident
    const short8* ap = (const short8*)(cpk + (size_t)kk * 5120);
    short8 Ah[5], Al[5];
#pragma unroll
    for (int cf = 0; cf < 5; cf++) {
      Ah[cf] = ap[(0 * 5 + cf) * 64 + lane];
      Al[cf] = ap[(1 * 5 + cf) * 64 + lane];
    }
    f32x4 v0 = xq[kk & 7][0], v1 = xq[kk & 7][1];
    if (kk + 8 < 16) {                       // refill 8 ahead
      xq[kk & 7][0] = *(const f32x4*)(xrow + (kk + 8) * 32);
      xq[kk & 7][1] = *(const f32x4*)(xrow + (kk + 8) * 32 + 4);
    }
    // split x into hi/lo bf16 + rne copy for xT
    short8 bh, bl; u16 rn[8];
#pragma unroll
    for (int j = 0; j < 4; j++) {
      u16 h, l;
      split2(v0[j], h, l); bh[j] = h;     bl[j] = l;     rn[j]     = f2bf(v0[j]);
      split2(v1[j], h, l); bh[j + 4] = h; bl[j + 4] = l; rn[j + 4] = f2bf(v1[j]);
    }
    // xT stores: d = kk*32 + lhi*8 + j, col n = nw
#pragma unroll
    for (int j = 0; j < 8; j++)
      xT[(size_t)(kk * 32 + lhi * 8 + j) * MT_ + nw] = rn[j];
    // 15 MFMA: hh + hl + lh per column-fragment
#pragma unroll
    for (int cf = 0; cf < 5; cf++) {
      acc[cf] = __builtin_amdgcn_mfma_f32_16x16x32_bf16(Ah[cf], bh, acc[cf], 0, 0, 0);
      acc[cf] = __builtin_amdgcn_mfma_f32_16x16x32_bf16(Ah[cf], bl, acc[cf], 0, 0, 0);
      acc[cf] = __builtin_amdgcn_mfma_f32_16x16x32_bf16(Al[cf], bh, acc[cf], 0, 0, 0);
    }
  }

  // BN + softmax over 80 c for this lane's n: 20 local + shfl over lhi groups
  f32x4 sc4[5], sh4[5];
#pragma unroll
  for (int cf = 0; cf < 5; cf++) {
    sc4[cf] = *(const f32x4*)&bn_sc[cf * 16 + lhi * 4];
    sh4[cf] = *(const f32x4*)&bn_sh[cf * 16 + lhi * 4];
  }
  float lv[5][4], mx = -3.0e38f;
#pragma unroll
  for (int cf = 0; cf < 5; cf++)
#pragma unroll
    for (int r = 0; r < 4; r++) {
      lv[cf][r] = fmaf(acc[cf][r], sc4[cf][r], sh4[cf][r]);
      mx = fmaxf(mx, lv[cf][r]);
    }
  float M = mx;
  M = fmaxf(M, __shfl_xor(M, 16)); M = fmaxf(M, __shfl_xor(M, 32));
  float s = 0.0f;
#pragma unroll
  for (int cf = 0; cf < 5; cf++)
#pragma unroll
    for (int r = 0; r < 4; r++) { lv[cf][r] = __expf(lv[cf][r] - M); s += lv[cf][r]; }
  s += __shfl_xor(s, 16); s += __shfl_xor(s, 32);
  float inv = 1.0f / s;

#pragma unroll
  for (int cf = 0; cf < 4; cf++) {          // c 64..79 dropped
#pragma unroll
    for (int r = 0; r < 4; r++) {
      float a = lv[cf][r] * inv;
      aTs[cf * 16 + lhi * 4 + r][w * 16 + l15] = f2bf(a);
      float ps = a;                          // a_sum over this wave's 16 n
      ps += __shfl_xor(ps, 1); ps += __shfl_xor(ps, 2);
      ps += __shfl_xor(ps, 4); ps += __shfl_xor(ps, 8);
      if (l15 == 0) atomicAdd(&asum_g[b * 64 + cf * 16 + lhi * 4 + r], ps);
    }
  }
  __syncthreads();
  // aT writeout: thread t -> k=t>>2, 16-n segment t&3 (32B, coalesced)
  {
    int k = t >> 2, seg = t & 3;
    short8 u0 = *(const short8*)&aTs[k][seg * 16];
    short8 u1 = *(const short8*)&aTs[k][seg * 16 + 8];
    u16* dp = aT + (size_t)k * MT_ + n0 + seg * 16;
    *(short8*)&dp[0] = u0;
    *(short8*)&dp[8] = u1;
  }
}

// ---------------------------------------------------------------------------
// K2 (MFMA): vlad[b][d][k] = sum_n xT[d][n]*aT[k][n] - asum*c2 fused.
// Both operands in perfect fragment order (16B loads). 1024 blocks =
// (dt:32 of 16 d) x (b:32); b = id&31 keeps batch on one XCD (aT/xT L2).
// 4 waves = 4 k-fragments; depth-12 rotating prefetch (6 KB/CU in flight).
// C[m=d][col=k] = output layout -> coalesced 64B stores, fused ssq.
// ---------------------------------------------------------------------------
__global__ __launch_bounds__(256, 4) void k_vlad(
    const u16* __restrict__ xT, const u16* __restrict__ aT,
    const float* __restrict__ asum_g, const float* __restrict__ c2,
    float* __restrict__ vlad, float* __restrict__ ssq) {
  __shared__ float wred[4];

  int t = threadIdx.x;
  int lane = t & 63;
  int w = t >> 6;                   // k-fragment
  int l15 = lane & 15, lhi = lane >> 4;
  int id = blockIdx.x;
  int b = id & 31;
  int d0 = (id >> 5) * 16;

  const u16* xbase = xT + (size_t)(d0 + l15) * MT_ + b * 1024 + lhi * 8;
  const u16* abase = aT + (size_t)(w * 16 + l15) * MT_ + b * 1024 + lhi * 8;

  f32x4 acc = (f32x4)0.0f;
  short8 Af[12], Bf[12];
#pragma unroll
  for (int p = 0; p < 12; p++) {
    Af[p] = *(const short8*)(xbase + p * 32);
    Bf[p] = *(const short8*)(abase + p * 32);
  }
#pragma unroll
  for (int cc = 0; cc < 32; cc++) {
    short8 a = Af[cc % 12], bb = Bf[cc % 12];
    if (cc + 12 < 32) {
      Af[cc % 12] = *(const short8*)(xbase + (cc + 12) * 32);
      Bf[cc % 12] = *(const short8*)(abase + (cc + 12) * 32);
    }
    acc = __builtin_amdgcn_mfma_f32_16x16x32_bf16(a, bb, acc, 0, 0, 0);
  }

  // epilogue: C row = lhi*4+r = d-local, col = l15 -> k = w*16+l15
  int k = w * 16 + l15;
  float av = asum_g[b * 64 + k];
  float psq = 0.0f;
#pragma unroll
  for (int r = 0; r < 4; r++) {
    int d = d0 + lhi * 4 + r;
    float val = acc[r] - av * c2[(size_t)d * 64 + k];
    vlad[(size_t)b * 32768 + (size_t)d * 64 + k] = val;
    psq += val * val;
  }
  psq += __shfl_xor(psq, 1);  psq += __shfl_xor(psq, 2);
  psq += __shfl_xor(psq, 4);  psq += __shfl_xor(psq, 8);
  psq += __shfl_xor(psq, 16); psq += __shfl_xor(psq, 32);
  if (lane == 0) wred[w] = psq;
  __syncthreads();
  if (t == 0) atomicAdd(&ssq[b], wred[0] + wred[1] + wred[2] + wred[3]);
}

// ---------------------------------------------------------------------------
// K3: out = vlad * scale[b]  (vlad is already in output layout [b][d][k])
// ---------------------------------------------------------------------------
__global__ __launch_bounds__(256) void k_out(const float* __restrict__ vlad,
                                             const float* __restrict__ ssq,
                                             float* __restrict__ out) {
  int bb = blockIdx.x >> 5;         // 32 blocks per batch
  float S = ssq[bb];
  float n1 = sqrtf(S + 1e-12f);
  float n2 = sqrtf(S / (S + 1e-12f) + 1e-12f);
  float s = 1.0f / (n1 * n2);
  size_t idx = ((size_t)blockIdx.x * 256 + threadIdx.x) * 4;
  f32x4 v = *(const f32x4*)&vlad[idx];
  f32x4 o;
#pragma unroll
  for (int j = 0; j < 4; j++) o[j] = v[j] * s;
  *(f32x4*)&out[idx] = o;
}

extern "C" void kernel_launch(void* const* d_in, const int* in_sizes, int n_in,
                              void* d_out, int out_size, void* d_ws, size_t ws_size,
                              hipStream_t stream) {
  const float* x        = (const float*)d_in[0];
  const float* clusters = (const float*)d_in[1];
  const float* clusters2= (const float*)d_in[2];
  const float* bn_w     = (const float*)d_in[3];
  const float* bn_b     = (const float*)d_in[4];
  const float* bn_m     = (const float*)d_in[5];
  const float* bn_v     = (const float*)d_in[6];
  float* out = (float*)d_out;

  char* ws = (char*)d_ws;
  u16*   aT    = (u16*)ws;                              // 64*32768 bf16 = 4 MB
  u16*   xT    = (u16*)(ws + (size_t)4 * 1048576);      // 512*32768 bf16 = 32 MB
  float* vlad  = (float*)(ws + (size_t)36 * 1048576);   // 4 MB
  u16*   cpk   = (u16*)(ws + (size_t)40 * 1048576);     // 160 KB
  float* bn_sc = (float*)(ws + (size_t)40 * 1048576 + 262144);
  float* bn_sh = bn_sc + KG_;
  float* asum  = bn_sh + KG_;                           // 2048 f32
  float* ssq   = asum + B_ * K_;                        // 32 f32

  k_prep<<<20, 256, 0, stream>>>(clusters, bn_w, bn_b, bn_m, bn_v,
                                 cpk, bn_sc, bn_sh, asum, ssq);
  k_assign<<<512, 256, 0, stream>>>(x, cpk, bn_sc, bn_sh, aT, xT, asum);
  k_vlad<<<1024, 256, 0, stream>>>(xT, aT, asum, clusters2, vlad, ssq);
  k_out<<<1024, 256, 0, stream>>>(vlad, ssq, out);
}

// Round 8
// 152.743 us; speedup vs baseline: 1.0704x; 1.0704x over previous
//
#include <hip/hip_runtime.h>

typedef unsigned short u16;
typedef float f32x4 __attribute__((ext_vector_type(4)));
typedef short short8 __attribute__((ext_vector_type(8)));

#define B_ 32
#define N_ 1024
#define D_ 512
#define K_ 64
#define KG_ 80
#define MT_ 32768          // total rows B*N

__device__ __forceinline__ u16 f2bf(float f) {
  union { float f; unsigned u; } x; x.f = f;
  unsigned u = x.u;
  u += 0x7FFFu + ((u >> 16) & 1u);          // RNE, finite data
  return (u16)(u >> 16);
}
__device__ __forceinline__ void split2(float v, u16& h, u16& l) {
  union { float f; unsigned u; } x; x.f = v;
  unsigned hu = x.u & 0xFFFF0000u;          // truncate -> hi
  h = (u16)(hu >> 16);
  union { unsigned u; float f; } hf; hf.u = hu;
  l = f2bf(v - hf.f);                       // exact remainder, rne -> lo
}

// ---------------------------------------------------------------------------
// K0: BN fold; zero accumulators; pack clusters into MFMA A-fragments (hi/lo).
// cpk layout: [kk=16][h=2][cf=5][lane=64][j=8] u16
//   element = clusters[d=kk*32+(lane>>4)*8+j][col=cf*16+(lane&15)]
// ---------------------------------------------------------------------------
__global__ void k_prep(const float* __restrict__ clusters,
                       const float* __restrict__ bn_w, const float* __restrict__ bn_b,
                       const float* __restrict__ bn_m, const float* __restrict__ bn_v,
                       u16* __restrict__ cpk, float* __restrict__ bn_sc,
                       float* __restrict__ bn_sh,
                       float* __restrict__ asum, float* __restrict__ ssq) {
  int t = blockIdx.x * 256 + threadIdx.x;
  if (t < KG_) {
    float sc = bn_w[t] * rsqrtf(bn_v[t] + 1e-5f);
    bn_sc[t] = sc;
    bn_sh[t] = bn_b[t] - bn_m[t] * sc;
  }
  if (t < B_ * K_) asum[t] = 0.0f;
  if (t < B_) ssq[t] = 0.0f;
  if (t < 5120) {                            // (kk*5+cf)*64 + lane
    int grp = t >> 6;
    int kk = grp / 5, cf = grp % 5;
    int lane = t & 63;
    int col = cf * 16 + (lane & 15);
#pragma unroll
    for (int j = 0; j < 8; j++) {
      int d = kk * 32 + ((lane >> 4) << 3) + j;
      float v = clusters[(size_t)d * 80 + col];
      u16 h, l; split2(v, h, l);
      cpk[(size_t)kk * 5120 + ((0 * 5 + cf) * 64 + lane) * 8 + j] = h;
      cpk[(size_t)kk * 5120 + ((1 * 5 + cf) * 64 + lane) * 8 + j] = l;
    }
  }
}

// ---------------------------------------------------------------------------
// K1 (MFMA, logits^T): C[c=80][n], A = clusters frags (cpk, L2-hot),
// B = x rows natural layout (16B loads). K-SPLIT: 8 waves'-worth of work in
// 4 waves x 2 K-halves -> 1024 blocks x 32 n = 16 waves/CU (2x round 7).
// Per wave: 8 kk steps, full-depth (4-slot) static register prefetch of x,
// no barriers in the loop. LDS merge of K-halves, in-wave softmax (shfl),
// aT bounce -> coalesced stores, asum atomics. No xT write.
// ---------------------------------------------------------------------------
__global__ __launch_bounds__(256, 3) void k_assign(
    const float* __restrict__ x, const u16* __restrict__ cpk,
    const float* __restrict__ bn_sc, const float* __restrict__ bn_sh,
    u16* __restrict__ aT, float* __restrict__ asum_g) {
  __shared__ f32x4 mrg[2][5][64];   // [g][cf][lane] K-half-1 partials
  __shared__ u16 aTs[64][40];       // [c][n_local 0..31], pad->80B rows

  int t = threadIdx.x;
  int lane = t & 63;
  int w = t >> 6;
  int g = w & 1;                    // n-group (16 n each)
  int h = w >> 1;                   // K-half
  int l15 = lane & 15, lhi = lane >> 4;
  int n0 = blockIdx.x * 32;
  int b = blockIdx.x >> 5;          // 32 blocks per batch
  int nw = n0 + g * 16 + l15;
  int kk0 = h * 8;

  const float* xrow = x + (size_t)nw * 512 + lhi * 8;

  f32x4 acc[5];
#pragma unroll
  for (int cf = 0; cf < 5; cf++) acc[cf] = (f32x4)0.0f;

  f32x4 xq[4][2];                   // 4-deep prefetch, fully static
#pragma unroll
  for (int p = 0; p < 4; p++) {
    xq[p][0] = *(const f32x4*)(xrow + (kk0 + p) * 32);
    xq[p][1] = *(const f32x4*)(xrow + (kk0 + p) * 32 + 4);
  }

#pragma unroll
  for (int s = 0; s < 8; s++) {
    int kk = kk0 + s;
    const short8* ap = (const short8*)(cpk + (size_t)kk * 5120);
    short8 Ah[5], Al[5];
#pragma unroll
    for (int cf = 0; cf < 5; cf++) {
      Ah[cf] = ap[cf * 64 + lane];
      Al[cf] = ap[(5 + cf) * 64 + lane];
    }
    f32x4 v0 = xq[s & 3][0], v1 = xq[s & 3][1];
    if (s + 4 < 8) {
      xq[s & 3][0] = *(const f32x4*)(xrow + (kk + 4) * 32);
      xq[s & 3][1] = *(const f32x4*)(xrow + (kk + 4) * 32 + 4);
    }
    short8 bh, bl;
#pragma unroll
    for (int j = 0; j < 4; j++) {
      u16 hh, ll;
      split2(v0[j], hh, ll); bh[j] = hh;     bl[j] = ll;
      split2(v1[j], hh, ll); bh[j + 4] = hh; bl[j + 4] = ll;
    }
#pragma unroll
    for (int cf = 0; cf < 5; cf++) {
      acc[cf] = __builtin_amdgcn_mfma_f32_16x16x32_bf16(Ah[cf], bh, acc[cf], 0, 0, 0);
      acc[cf] = __builtin_amdgcn_mfma_f32_16x16x32_bf16(Ah[cf], bl, acc[cf], 0, 0, 0);
      acc[cf] = __builtin_amdgcn_mfma_f32_16x16x32_bf16(Al[cf], bh, acc[cf], 0, 0, 0);
    }
  }

  if (h == 1) {
#pragma unroll
    for (int cf = 0; cf < 5; cf++) mrg[g][cf][lane] = acc[cf];
  }
  __syncthreads();

  if (h == 0) {
#pragma unroll
    for (int cf = 0; cf < 5; cf++) acc[cf] += mrg[g][cf][lane];

    // BN + softmax: lane holds 20 c's of its n; full 80 via lhi (shfl 16,32)
    f32x4 sc4[5], sh4[5];
#pragma unroll
    for (int cf = 0; cf < 5; cf++) {
      sc4[cf] = *(const f32x4*)&bn_sc[cf * 16 + lhi * 4];
      sh4[cf] = *(const f32x4*)&bn_sh[cf * 16 + lhi * 4];
    }
    float lv[5][4], mx = -3.0e38f;
#pragma unroll
    for (int cf = 0; cf < 5; cf++)
#pragma unroll
      for (int r = 0; r < 4; r++) {
        lv[cf][r] = fmaf(acc[cf][r], sc4[cf][r], sh4[cf][r]);
        mx = fmaxf(mx, lv[cf][r]);
      }
    float M = mx;
    M = fmaxf(M, __shfl_xor(M, 16)); M = fmaxf(M, __shfl_xor(M, 32));
    float s = 0.0f;
#pragma unroll
    for (int cf = 0; cf < 5; cf++)
#pragma unroll
      for (int r = 0; r < 4; r++) { lv[cf][r] = __expf(lv[cf][r] - M); s += lv[cf][r]; }
    s += __shfl_xor(s, 16); s += __shfl_xor(s, 32);
    float inv = 1.0f / s;

#pragma unroll
    for (int cf = 0; cf < 4; cf++) {          // c 64..79 dropped
#pragma unroll
      for (int r = 0; r < 4; r++) {
        float a = lv[cf][r] * inv;
        aTs[cf * 16 + lhi * 4 + r][g * 16 + l15] = f2bf(a);
        float ps = a;                          // reduce over 16 n (l15 bits)
        ps += __shfl_xor(ps, 1); ps += __shfl_xor(ps, 2);
        ps += __shfl_xor(ps, 4); ps += __shfl_xor(ps, 8);
        if (l15 == 0) atomicAdd(&asum_g[b * 64 + cf * 16 + lhi * 4 + r], ps);
      }
    }
  }
  __syncthreads();
  // aT writeout: 64 c rows x 32 n, 4 threads/row x 16B
  {
    int k = t >> 2, seg = t & 3;
    short8 uu = *(const short8*)&aTs[k][seg * 8];
    *(short8*)(aT + (size_t)k * MT_ + n0 + seg * 8) = uu;
  }
}

// ---------------------------------------------------------------------------
// K2 (MFMA): vlad[b][d][k] = sum_n x[n][d]*aT[k][n] - asum*c2.
// 1024 blocks = (dt:32 of 16 d) x (b:32); id%8=b%8 pins batch to one XCD.
// x read COALESCED [n][d] (L3-hot from k_assign), converted+transposed into
// double-buffered LDS xs[16][n-chunk]; aT B-frags direct 16B (L2-hot).
// Chunk=128 n (4 MFMA/wave), next chunk's globals issued before compute.
// C rows=d, cols=k  -> output layout, fused -asum*c2 + ssq.
// ---------------------------------------------------------------------------
__global__ __launch_bounds__(256, 4) void k_vlad(
    const float* __restrict__ x, const u16* __restrict__ aT,
    const float* __restrict__ asum_g, const float* __restrict__ c2,
    float* __restrict__ vlad, float* __restrict__ ssq) {
  __shared__ u16 xs[2][16][136];    // [buf][d_local][n_chunk 0..127] pad 8
  __shared__ float wred[4];

  int t = threadIdx.x;
  int lane = t & 63;
  int w = t >> 6;                   // k-fragment
  int id = blockIdx.x;
  int b = id & 31;
  int d0 = (id >> 5) * 16;
  int l15 = lane & 15, lhi = lane >> 4;

  const float* xb = x + (size_t)b * 524288 + d0;
  const u16* abase = aT + (size_t)(w * 16 + l15) * MT_ + b * 1024 + lhi * 8;

  int nl = t >> 1;                  // 0..127 chunk-local n
  int dseg = (t & 1) * 8;           // 8 consecutive d per thread

  f32x4 acc = (f32x4)0.0f;

  // prologue: stage chunk 0
  {
    f32x4 s0 = *(const f32x4*)&xb[(size_t)nl * 512 + dseg];
    f32x4 s1 = *(const f32x4*)&xb[(size_t)nl * 512 + dseg + 4];
#pragma unroll
    for (int i = 0; i < 4; i++) {
      xs[0][dseg + i][nl]     = f2bf(s0[i]);
      xs[0][dseg + 4 + i][nl] = f2bf(s1[i]);
    }
  }

  for (int c = 0; c < 8; c++) {
    __syncthreads();                // xs[c&1] ready
    f32x4 p0, p1;
    if (c < 7) {                    // issue next chunk's globals early
      p0 = *(const f32x4*)&xb[(size_t)((c + 1) * 128 + nl) * 512 + dseg];
      p1 = *(const f32x4*)&xb[(size_t)((c + 1) * 128 + nl) * 512 + dseg + 4];
    }
    short8 Bf[4];
#pragma unroll
    for (int ns = 0; ns < 4; ns++)
      Bf[ns] = *(const short8*)(abase + c * 128 + ns * 32);
#pragma unroll
    for (int ns = 0; ns < 4; ns++) {
      short8 Afr = *(const short8*)&xs[c & 1][l15][ns * 32 + lhi * 8];
      acc = __builtin_amdgcn_mfma_f32_16x16x32_bf16(Afr, Bf[ns], acc, 0, 0, 0);
    }
    __syncthreads();                // all reads of xs[c&1] done
    if (c < 7) {
#pragma unroll
      for (int i = 0; i < 4; i++) {
        xs[(c + 1) & 1][dseg + i][nl]     = f2bf(p0[i]);
        xs[(c + 1) & 1][dseg + 4 + i][nl] = f2bf(p1[i]);
      }
    }
  }

  // epilogue: C row = lhi*4+r = d-local, col = l15 -> k = w*16+l15
  int k = w * 16 + l15;
  float av = asum_g[b * 64 + k];
  float psq = 0.0f;
#pragma unroll
  for (int r = 0; r < 4; r++) {
    int d = d0 + lhi * 4 + r;
    float val = acc[r] - av * c2[(size_t)d * 64 + k];
    vlad[(size_t)b * 32768 + (size_t)d * 64 + k] = val;
    psq += val * val;
  }
  psq += __shfl_xor(psq, 1);  psq += __shfl_xor(psq, 2);
  psq += __shfl_xor(psq, 4);  psq += __shfl_xor(psq, 8);
  psq += __shfl_xor(psq, 16); psq += __shfl_xor(psq, 32);
  if (lane == 0) wred[w] = psq;
  __syncthreads();
  if (t == 0) atomicAdd(&ssq[b], wred[0] + wred[1] + wred[2] + wred[3]);
}

// ---------------------------------------------------------------------------
// K3: out = vlad * scale[b]  (vlad already in output layout [b][d][k])
// ---------------------------------------------------------------------------
__global__ __launch_bounds__(256) void k_out(const float* __restrict__ vlad,
                                             const float* __restrict__ ssq,
                                             float* __restrict__ out) {
  int bb = blockIdx.x >> 5;         // 32 blocks per batch
  float S = ssq[bb];
  float n1 = sqrtf(S + 1e-12f);
  float n2 = sqrtf(S / (S + 1e-12f) + 1e-12f);
  float s = 1.0f / (n1 * n2);
  size_t idx = ((size_t)blockIdx.x * 256 + threadIdx.x) * 4;
  f32x4 v = *(const f32x4*)&vlad[idx];
  f32x4 o;
#pragma unroll
  for (int j = 0; j < 4; j++) o[j] = v[j] * s;
  *(f32x4*)&out[idx] = o;
}

extern "C" void kernel_launch(void* const* d_in, const int* in_sizes, int n_in,
                              void* d_out, int out_size, void* d_ws, size_t ws_size,
                              hipStream_t stream) {
  const float* x        = (const float*)d_in[0];
  const float* clusters = (const float*)d_in[1];
  const float* clusters2= (const float*)d_in[2];
  const float* bn_w     = (const float*)d_in[3];
  const float* bn_b     = (const float*)d_in[4];
  const float* bn_m     = (const float*)d_in[5];
  const float* bn_v     = (const float*)d_in[6];
  float* out = (float*)d_out;

  char* ws = (char*)d_ws;
  u16*   aT    = (u16*)ws;                              // 64*32768 bf16 = 4 MB
  float* vlad  = (float*)(ws + (size_t)4 * 1048576);    // 4 MB
  u16*   cpk   = (u16*)(ws + (size_t)8 * 1048576);      // 160 KB
  float* bn_sc = (float*)(ws + (size_t)8 * 1048576 + 262144);
  float* bn_sh = bn_sc + KG_;
  float* asum  = bn_sh + KG_;                           // 2048 f32
  float* ssq   = asum + B_ * K_;                        // 32 f32

  k_prep<<<20, 256, 0, stream>>>(clusters, bn_w, bn_b, bn_m, bn_v,
                                 cpk, bn_sc, bn_sh, asum, ssq);
  k_assign<<<1024, 256, 0, stream>>>(x, cpk, bn_sc, bn_sh, aT, asum);
  k_vlad<<<1024, 256, 0, stream>>>(x, aT, asum, clusters2, vlad, ssq);
  k_out<<<1024, 256, 0, stream>>>(vlad, ssq, out);
}